// Round 1
// baseline (80.819 us; speedup 1.0000x reference)
//
#include <hip/hip_runtime.h>

// Bilateral filter, N=2, C=F=16, H=W=256, WIN=3 (49 taps), fp32.
// sigma_s=0.7, sigma_v=0.1, REG=1e-20, zero padding (patches are 0 outside).
//
// Strategy:
//  - 16x16 output tile per 256-thread block; grid (16,16,2) = 512 blocks.
//  - Embed halo (22x22, 16 ch) staged in LDS channels-last as float4[4][22][23]
//    -> 4x ds_read_b128 per tap for the distance computation.
//  - Weight = exp2(-50*log2e*d2 - (r2/0.98)*log2e)  (value+spatial fused).
//  - EXACT skip: if all 64 lanes' weight underflowed to 0.0f, the x-phase
//    (16 global loads + 16 FMAs) contributes exactly 0 -> skip it.
//  - x_in is NOT staged: live taps are rare on this data; loads are coalesced
//    and L1/L2-resident.

#define TS 16      // tile size
#define HS 22      // halo size = TS + 6
#define HP 23      // padded LDS row length (float4 units)

#define CH 16
#define HW 256
#define PLANE (HW * HW)   // 65536

__global__ __launch_bounds__(256, 2)
void bilat_kernel(const float* __restrict__ embed,
                  const float* __restrict__ xin,
                  float* __restrict__ out) {
    __shared__ float4 sE[4][HS][HP];   // 4*22*23*16 = 32384 B

    const int tx = threadIdx.x;
    const int ty = threadIdx.y;
    const int tid = ty * TS + tx;
    const int x0 = blockIdx.x * TS;
    const int y0 = blockIdx.y * TS;
    const int n  = blockIdx.z;

    const float* eb = embed + (size_t)n * CH * PLANE;
    const float* xb = xin   + (size_t)n * CH * PLANE;

    // ---- stage embed halo (zero outside image) ----
    for (int pos = tid; pos < HS * HS; pos += 256) {
        const int hy = pos / HS;
        const int hx = pos - hy * HS;
        const int gy = y0 - 3 + hy;
        const int gx = x0 - 3 + hx;
        const bool ok = ((unsigned)gy < (unsigned)HW) && ((unsigned)gx < (unsigned)HW);
        const float* p = eb + (size_t)gy * HW + gx;   // only deref'd if ok
        #pragma unroll
        for (int g = 0; g < 4; ++g) {
            float4 v;
            if (ok) {
                v.x = p[(4 * g + 0) * PLANE];
                v.y = p[(4 * g + 1) * PLANE];
                v.z = p[(4 * g + 2) * PLANE];
                v.w = p[(4 * g + 3) * PLANE];
            } else {
                v = make_float4(0.f, 0.f, 0.f, 0.f);
            }
            sE[g][hy][hx] = v;
        }
    }
    __syncthreads();

    // center embedding
    const float4 c0 = sE[0][ty + 3][tx + 3];
    const float4 c1 = sE[1][ty + 3][tx + 3];
    const float4 c2 = sE[2][ty + 3][tx + 3];
    const float4 c3 = sE[3][ty + 3][tx + 3];

    float acc[CH];
    #pragma unroll
    for (int c = 0; c < CH; ++c) acc[c] = 0.f;
    float wsum = 0.f;

    // constants: -0.5/sigma_v^2 * log2(e) = -50*1.4426950408889634
    const float CV = -72.13475204444817f;
    // -0.5/sigma_s^2 * log2(e) = -(1/0.98)*1.4426950408889634
    const float CS = -1.4721377968255749f;

    for (int dy = 0; dy < 7; ++dy) {
        const int hy  = ty + dy;
        const int gyy = y0 + ty + dy - 3;
        const float fy2 = (float)((dy - 3) * (dy - 3));
        #pragma unroll
        for (int dx = 0; dx < 7; ++dx) {
            const int hx = tx + dx;
            const float4 e0 = sE[0][hy][hx];
            const float4 e1 = sE[1][hy][hx];
            const float4 e2 = sE[2][hy][hx];
            const float4 e3 = sE[3][hy][hx];

            float s0 = 0.f, s1 = 0.f, s2 = 0.f, s3 = 0.f;
            #define D2ACC(E, C) do {                                  \
                float t0 = (E).x - (C).x, t1 = (E).y - (C).y,         \
                      t2 = (E).z - (C).z, t3 = (E).w - (C).w;         \
                s0 = fmaf(t0, t0, s0); s1 = fmaf(t1, t1, s1);         \
                s2 = fmaf(t2, t2, s2); s3 = fmaf(t3, t3, s3);         \
            } while (0)
            D2ACC(e0, c0); D2ACC(e1, c1); D2ACC(e2, c2); D2ACC(e3, c3);
            #undef D2ACC
            const float d2 = (s0 + s1) + (s2 + s3);

            const float r2 = fy2 + (float)((dx - 3) * (dx - 3));
            const float t  = fmaf(d2, CV, r2 * CS);
#if __has_builtin(__builtin_amdgcn_exp2f)
            const float w = __builtin_amdgcn_exp2f(t);
#else
            const float w = exp2f(t);
#endif
            wsum += w;

            // EXACT skip: if w == 0.0f on every lane, x-phase adds exactly 0.
            if (__any(w != 0.0f)) {
                const int gxx = x0 + tx + dx - 3;
                if (((unsigned)gyy < (unsigned)HW) && ((unsigned)gxx < (unsigned)HW)) {
                    const float* px = xb + (size_t)gyy * HW + gxx;
                    #pragma unroll
                    for (int c = 0; c < CH; ++c)
                        acc[c] = fmaf(w, px[(size_t)c * PLANE], acc[c]);
                }
            }
        }
    }

    const float rw = 1.0f / (wsum + 1e-20f);

    float* po = out + (size_t)n * CH * PLANE + (size_t)(y0 + ty) * HW + (x0 + tx);
    #pragma unroll
    for (int c = 0; c < CH; ++c)
        po[(size_t)c * PLANE] = acc[c] * rw;
}

extern "C" void kernel_launch(void* const* d_in, const int* in_sizes, int n_in,
                              void* d_out, int out_size, void* d_ws, size_t ws_size,
                              hipStream_t stream) {
    const float* embed = (const float*)d_in[0];
    const float* xin   = (const float*)d_in[1];
    float* out = (float*)d_out;

    dim3 block(TS, TS, 1);
    dim3 grid(HW / TS, HW / TS, 2);
    bilat_kernel<<<grid, block, 0, stream>>>(embed, xin, out);
}

// Round 4
// 80.115 us; speedup vs baseline: 1.0088x; 1.0088x over previous
//
#include <hip/hip_runtime.h>
#include <hip/hip_fp16.h>

// Bilateral filter, N=2, C=F=16, H=W=256, WIN=3 (49 taps), fp32 in/out.
// Round 2 kernel, resubmitted (rounds 2 and 3 both hit GPUAcquisitionTimeout;
// never measured): embed halo staged in LDS as packed fp16 (half the LDS
// bytes of round 1), distance computed with v_pk_fma_f16. Exact-skip of the
// x-phase when all 64 lanes' weights underflowed to 0 (always true on this
// data except the center tap). Full 49-tap unroll for ILP (TLP capped at
// 2 waves/SIMD by grid size).

#define TS 16      // tile size
#define HS 22      // halo = TS + 6
#define HP 23      // padded LDS row (in 16B units) -> odd stride, no conflicts

#define CH 16
#define HW 256
#define PLANE (HW * HW)

union alignas(16) H8 {
    float4  f4;
    __half2 h[4];
};

__global__ __launch_bounds__(256, 2)
void bilat_kernel(const float* __restrict__ embed,
                  const float* __restrict__ xin,
                  float* __restrict__ out) {
    __shared__ H8 sH[2][HS][HP];   // 2*22*23*16 = 16192 B

    const int tx = threadIdx.x;
    const int ty = threadIdx.y;
    const int tid = ty * TS + tx;
    const int x0 = blockIdx.x * TS;
    const int y0 = blockIdx.y * TS;
    const int n  = blockIdx.z;

    const float* eb = embed + (size_t)n * CH * PLANE;
    const float* xb = xin   + (size_t)n * CH * PLANE;

    // ---- stage embed halo as fp16 pairs (zero outside image) ----
    for (int pos = tid; pos < HS * HS; pos += 256) {
        const int hy = pos / HS;
        const int hx = pos - hy * HS;
        const int gy = y0 - 3 + hy;
        const int gx = x0 - 3 + hx;
        const bool ok = ((unsigned)gy < (unsigned)HW) && ((unsigned)gx < (unsigned)HW);
        H8 v0, v1;
        if (ok) {
            const float* p = eb + (size_t)gy * HW + gx;
            #pragma unroll
            for (int k = 0; k < 4; ++k) {
                v0.h[k] = __float22half2_rn(
                    make_float2(p[(size_t)(2*k    ) * PLANE], p[(size_t)(2*k + 1) * PLANE]));
                v1.h[k] = __float22half2_rn(
                    make_float2(p[(size_t)(2*k + 8) * PLANE], p[(size_t)(2*k + 9) * PLANE]));
            }
        } else {
            v0.f4 = make_float4(0.f, 0.f, 0.f, 0.f);
            v1.f4 = v0.f4;
        }
        sH[0][hy][hx] = v0;
        sH[1][hy][hx] = v1;
    }
    __syncthreads();

    const H8 C0 = sH[0][ty + 3][tx + 3];
    const H8 C1 = sH[1][ty + 3][tx + 3];

    float acc[CH];
    #pragma unroll
    for (int c = 0; c < CH; ++c) acc[c] = 0.f;
    float wsum = 0.f;

    // -0.5/sigma_v^2 * log2(e) = -50*1.4426950408889634
    const float CV = -72.13475204444817f;
    // -0.5/sigma_s^2 * log2(e) = -(1/0.98)*1.4426950408889634
    const float CS = -1.4721377968255749f;

    #pragma unroll
    for (int dy = 0; dy < 7; ++dy) {
        const int hy  = ty + dy;
        const int gyy = y0 + ty + dy - 3;
        const float fy2 = (float)((dy - 3) * (dy - 3));
        #pragma unroll
        for (int dx = 0; dx < 7; ++dx) {
            const int hx = tx + dx;
            const H8 E0 = sH[0][hy][hx];
            const H8 E1 = sH[1][hy][hx];

            __half2 s0 = __float2half2_rn(0.f);
            __half2 s1 = s0;
            #pragma unroll
            for (int k = 0; k < 4; ++k) {
                const __half2 d0 = __hsub2(E0.h[k], C0.h[k]);
                s0 = __hfma2(d0, d0, s0);
                const __half2 d1 = __hsub2(E1.h[k], C1.h[k]);
                s1 = __hfma2(d1, d1, s1);
            }
            const __half2 s = __hadd2(s0, s1);
            const float d2 = __low2float(s) + __high2float(s);

            const float r2 = fy2 + (float)((dx - 3) * (dx - 3));
            const float t  = fmaf(d2, CV, r2 * CS);
#if __has_builtin(__builtin_amdgcn_exp2f)
            const float w = __builtin_amdgcn_exp2f(t);
#else
            const float w = exp2f(t);
#endif
            wsum += w;

            // EXACT skip: if w == 0.0f on every lane, x-phase adds exactly 0.
            if (__any(w != 0.0f)) {
                const int gxx = x0 + tx + dx - 3;
                if (((unsigned)gyy < (unsigned)HW) && ((unsigned)gxx < (unsigned)HW)) {
                    const float* px = xb + (size_t)gyy * HW + gxx;
                    #pragma unroll
                    for (int c = 0; c < CH; ++c)
                        acc[c] = fmaf(w, px[(size_t)c * PLANE], acc[c]);
                }
            }
        }
    }

    const float rw = 1.0f / (wsum + 1e-20f);

    float* po = out + (size_t)n * CH * PLANE + (size_t)(y0 + ty) * HW + (x0 + tx);
    #pragma unroll
    for (int c = 0; c < CH; ++c)
        po[(size_t)c * PLANE] = acc[c] * rw;
}

extern "C" void kernel_launch(void* const* d_in, const int* in_sizes, int n_in,
                              void* d_out, int out_size, void* d_ws, size_t ws_size,
                              hipStream_t stream) {
    const float* embed = (const float*)d_in[0];
    const float* xin   = (const float*)d_in[1];
    float* out = (float*)d_out;

    dim3 block(TS, TS, 1);
    dim3 grid(HW / TS, HW / TS, 2);
    bilat_kernel<<<grid, block, 0, stream>>>(embed, xin, out);
}

// Round 6
// 79.657 us; speedup vs baseline: 1.0146x; 1.0057x over previous
//
#include <hip/hip_runtime.h>
#include <hip/hip_fp16.h>

// Bilateral filter, N=2, C=F=16, H=W=256, WIN=3 (49 taps), fp32 in/out.
// Round 5 kernel, resubmitted (round-5 bench hit GPUAcquisitionTimeout):
// center tap hoisted out of the loop (exact: d2=0, r2=0 -> w=1 for ANY
// data), so acc starts at x_center and wsum at 1. The 48 remaining taps
// keep the exact underflow-skip (__any(w!=0)) for the x-phase. 4-way wsum
// partials break the serial add chain. Embed halo in LDS as packed fp16
// (v_pk_fma_f16 distance). Kernel contribution is ~4-6us; dur_us is
// dominated by the harness 256MiB ws-poison fill (~43.5us) + restores.

#define TS 16      // tile size
#define HS 22      // halo = TS + 6
#define HP 23      // padded LDS row (in 16B units) -> odd stride, no conflicts

#define CH 16
#define HW 256
#define PLANE (HW * HW)

union alignas(16) H8 {
    float4  f4;
    __half2 h[4];
};

__global__ __launch_bounds__(256, 2)
void bilat_kernel(const float* __restrict__ embed,
                  const float* __restrict__ xin,
                  float* __restrict__ out) {
    __shared__ H8 sH[2][HS][HP];   // 2*22*23*16 = 16192 B

    const int tx = threadIdx.x;
    const int ty = threadIdx.y;
    const int tid = ty * TS + tx;
    const int x0 = blockIdx.x * TS;
    const int y0 = blockIdx.y * TS;
    const int n  = blockIdx.z;

    const float* eb = embed + (size_t)n * CH * PLANE;
    const float* xb = xin   + (size_t)n * CH * PLANE;

    // ---- stage embed halo as fp16 pairs (zero outside image) ----
    for (int pos = tid; pos < HS * HS; pos += 256) {
        const int hy = pos / HS;
        const int hx = pos - hy * HS;
        const int gy = y0 - 3 + hy;
        const int gx = x0 - 3 + hx;
        const bool ok = ((unsigned)gy < (unsigned)HW) && ((unsigned)gx < (unsigned)HW);
        H8 v0, v1;
        if (ok) {
            const float* p = eb + (size_t)gy * HW + gx;
            #pragma unroll
            for (int k = 0; k < 4; ++k) {
                v0.h[k] = __float22half2_rn(
                    make_float2(p[(size_t)(2*k    ) * PLANE], p[(size_t)(2*k + 1) * PLANE]));
                v1.h[k] = __float22half2_rn(
                    make_float2(p[(size_t)(2*k + 8) * PLANE], p[(size_t)(2*k + 9) * PLANE]));
            }
        } else {
            v0.f4 = make_float4(0.f, 0.f, 0.f, 0.f);
            v1.f4 = v0.f4;
        }
        sH[0][hy][hx] = v0;
        sH[1][hy][hx] = v1;
    }

    // ---- prefetch center x (the only guaranteed-live tap); latency hides
    //      under the staging drain + __syncthreads ----
    float acc[CH];
    {
        const float* pxc = xb + (size_t)(y0 + ty) * HW + (x0 + tx);
        #pragma unroll
        for (int c = 0; c < CH; ++c) acc[c] = pxc[(size_t)c * PLANE];
    }

    __syncthreads();

    const H8 C0 = sH[0][ty + 3][tx + 3];
    const H8 C1 = sH[1][ty + 3][tx + 3];

    // center tap: d2 = 0 exactly (E==C), r2 = 0 -> w = 1 exactly.
    float ws0 = 1.f, ws1 = 0.f, ws2 = 0.f, ws3 = 0.f;

    // -0.5/sigma_v^2 * log2(e) = -50*1.4426950408889634
    const float CV = -72.13475204444817f;
    // -0.5/sigma_s^2 * log2(e) = -(1/0.98)*1.4426950408889634
    const float CS = -1.4721377968255749f;

    #pragma unroll
    for (int dy = 0; dy < 7; ++dy) {
        const int hy  = ty + dy;
        const int gyy = y0 + ty + dy - 3;
        const float fy2 = (float)((dy - 3) * (dy - 3));
        #pragma unroll
        for (int dx = 0; dx < 7; ++dx) {
            if (dy == 3 && dx == 3) continue;   // center handled above
            const int hx = tx + dx;
            const H8 E0 = sH[0][hy][hx];
            const H8 E1 = sH[1][hy][hx];

            __half2 s0 = __float2half2_rn(0.f);
            __half2 s1 = s0;
            #pragma unroll
            for (int k = 0; k < 4; ++k) {
                const __half2 d0 = __hsub2(E0.h[k], C0.h[k]);
                s0 = __hfma2(d0, d0, s0);
                const __half2 d1 = __hsub2(E1.h[k], C1.h[k]);
                s1 = __hfma2(d1, d1, s1);
            }
            const __half2 s = __hadd2(s0, s1);
            const float d2 = __low2float(s) + __high2float(s);

            const float r2 = fy2 + (float)((dx - 3) * (dx - 3));
            const float t  = fmaf(d2, CV, r2 * CS);
#if __has_builtin(__builtin_amdgcn_exp2f)
            const float w = __builtin_amdgcn_exp2f(t);
#else
            const float w = exp2f(t);
#endif
            // 4-way partial wsum (break the serial dependence chain)
            if ((dx & 3) == 0)      ws0 += w;
            else if ((dx & 3) == 1) ws1 += w;
            else if ((dx & 3) == 2) ws2 += w;
            else                    ws3 += w;

            // EXACT skip: if w == 0.0f on every lane, x-phase adds exactly 0.
            if (__any(w != 0.0f)) {
                const int gxx = x0 + tx + dx - 3;
                if (((unsigned)gyy < (unsigned)HW) && ((unsigned)gxx < (unsigned)HW)) {
                    const float* px = xb + (size_t)gyy * HW + gxx;
                    #pragma unroll
                    for (int c = 0; c < CH; ++c)
                        acc[c] = fmaf(w, px[(size_t)c * PLANE], acc[c]);
                }
            }
        }
    }

    const float wsum = ((ws0 + ws1) + (ws2 + ws3));
    const float rw = 1.0f / (wsum + 1e-20f);

    float* po = out + (size_t)n * CH * PLANE + (size_t)(y0 + ty) * HW + (x0 + tx);
    #pragma unroll
    for (int c = 0; c < CH; ++c)
        po[(size_t)c * PLANE] = acc[c] * rw;
}

extern "C" void kernel_launch(void* const* d_in, const int* in_sizes, int n_in,
                              void* d_out, int out_size, void* d_ws, size_t ws_size,
                              hipStream_t stream) {
    const float* embed = (const float*)d_in[0];
    const float* xin   = (const float*)d_in[1];
    float* out = (float*)d_out;

    dim3 block(TS, TS, 1);
    dim3 grid(HW / TS, HW / TS, 2);
    bilat_kernel<<<grid, block, 0, stream>>>(embed, xin, out);
}